// Round 6
// baseline (319.586 us; speedup 1.0000x reference)
//
#include <hip/hip_runtime.h>
#include <hip/hip_bf16.h>
#include <hip/hip_fp16.h>
#include <math.h>

#define XW 4099
#define DSD 3
#define BSZ 8192
#define KP1 1696   // fc1 K padded: 1693 -> 1696 (multiple of 32, 16B-aligned rows)

typedef __attribute__((ext_vector_type(8))) _Float16 f16x8;
typedef __attribute__((ext_vector_type(4))) float    f32x4;

static __device__ __forceinline__ short f2h(float f) {
    union { _Float16 h; short s; } u;
    u.h = (_Float16)f;
    return u.s;
}

// ---------------------------------------------------------------------------
// Kernel 0: f32 -> f16 weight conversion with K-padding.  dst[N][Kp]
// ---------------------------------------------------------------------------
__global__ __launch_bounds__(256) void cvt_f16_pad(
    const float* __restrict__ src, short* __restrict__ dst,
    int N, int K, int Kp)
{
    const int tot = N * Kp;
    for (int i = blockIdx.x * 256 + threadIdx.x; i < tot; i += gridDim.x * 256) {
        const int n = i / Kp, k = i % Kp;
        dst[i] = (k < K) ? f2h(src[(size_t)n * K + k]) : (short)0;
    }
}

// ---------------------------------------------------------------------------
// Kernel 1: fused conv. conv1 = f32 VALU, ONE pass over k-positions with all
// 5 channels' accumulators live (acc[5][4][4] = 80 VGPR) so the 8x8 patch is
// loaded exactly once (16 ds_read_b128). Weights via 2 broadcast reads/kpos
// from a transposed [25][8] tile. conv2 = implicit-GEMM on MFMA (as r5).
// ---------------------------------------------------------------------------
__global__ __launch_bounds__(256, 4) void conv_fused(
    const float* __restrict__ x,
    const float* __restrict__ w1, const float* __restrict__ b1,
    const float* __restrict__ w2, const float* __restrict__ b2,
    short* __restrict__ act1)
{
    __shared__ __align__(16) float     img[64][68];    // 17.4 KB
    __shared__ __align__(16) _Float16  h1[5][32][36];  // 11.5 KB (i-stride 2304 B, row 72 B)
    __shared__ __align__(16) float     cw1t[25][8];    // conv1 w transposed [kpos][ch]
    __shared__ float cb1[5];
    __shared__ __align__(16) _Float16  w2f[16][136];   // conv2 B-matrix [ch][k], padded
    __shared__ float cb2s[16];
    __shared__ unsigned short koff[128];               // k -> byte offset into h1

    const int b = blockIdx.x;
    const int t = threadIdx.x;

    // ---- stage
    const float* xr = x + (size_t)b * XW + DSD;
    #pragma unroll
    for (int i = 0; i < 16; ++i) {
        const int idx = t + 256 * i;
        img[idx >> 6][idx & 63] = xr[idx];
    }
    if (t < 128)
        koff[t] = (t < 125)
            ? (unsigned short)((t / 25) * 2304 + ((t % 25) / 5) * 72 + (t % 5) * 2)
            : (unsigned short)0;
    if (t < 200) {                       // transpose conv1 weights: [kk][c]
        const int kk = t >> 3, c = t & 7;
        cw1t[kk][c] = (c < 5) ? w1[c * 25 + kk] : 0.f;
    }
    if (t >= 208 && t < 213) cb1[t - 208] = b1[t - 208];
    if (t >= 224 && t < 240) cb2s[t - 224] = (t - 224 < 10) ? b2[t - 224] : 0.f;
    for (int i = t; i < 16 * 136; i += 256) {
        const int c = i / 136, k = i % 136;
        _Float16 v = (_Float16)0.f;
        if (c < 10 && k < 125) v = (_Float16)w2[(c * 5 + k / 25) * 25 + (k % 25)];
        w2f[c][k] = v;
    }
    __syncthreads();

    // ---- conv1 + relu + pool (f32 VALU): 15x15 tiles of 2x2 pooled
    if (t < 225) {
        const int ty = t / 15, tx = t % 15;
        const int y0 = 4 * ty, x0 = 4 * tx;
        f32x4 pv[8][2];
        #pragma unroll
        for (int r = 0; r < 8; ++r) {
            pv[r][0] = *(const f32x4*)&img[y0 + r][x0];
            pv[r][1] = *(const f32x4*)&img[y0 + r][x0 + 4];
        }
        float acc[5][4][4];
        #pragma unroll
        for (int c = 0; c < 5; ++c) {
            const float bias = cb1[c];
            #pragma unroll
            for (int cy = 0; cy < 4; ++cy)
                #pragma unroll
                for (int cx = 0; cx < 4; ++cx) acc[c][cy][cx] = bias;
        }
        #pragma unroll
        for (int ky = 0; ky < 5; ++ky)
            #pragma unroll
            for (int kx = 0; kx < 5; ++kx) {
                const int kk = ky * 5 + kx;
                const f32x4 w03 = *(const f32x4*)&cw1t[kk][0];   // broadcast b128
                const float w4  = cw1t[kk][4];                   // broadcast b32
                #pragma unroll
                for (int cy = 0; cy < 4; ++cy)
                    #pragma unroll
                    for (int cx = 0; cx < 4; ++cx) {
                        const int px = cx + kx;
                        const float pvv = pv[cy + ky][px >> 2][px & 3];
                        acc[0][cy][cx] += pvv * w03[0];
                        acc[1][cy][cx] += pvv * w03[1];
                        acc[2][cy][cx] += pvv * w03[2];
                        acc[3][cy][cx] += pvv * w03[3];
                        acc[4][cy][cx] += pvv * w4;
                    }
            }
        #pragma unroll
        for (int c = 0; c < 5; ++c)
            #pragma unroll
            for (int sy = 0; sy < 2; ++sy)
                #pragma unroll
                for (int sx = 0; sx < 2; ++sx) {
                    const float m = fmaxf(
                        fmaxf(acc[c][2 * sy][2 * sx],     acc[c][2 * sy][2 * sx + 1]),
                        fmaxf(acc[c][2 * sy + 1][2 * sx], acc[c][2 * sy + 1][2 * sx + 1]));
                    h1[c][2 * ty + sy][2 * tx + sx] = (_Float16)fmaxf(m, 0.f);
                }
    }
    __syncthreads();

    // ---- conv2 via MFMA implicit GEMM
    short* outr = act1 + (size_t)b * KP1;
    {
        const int wv_ = t >> 6, lane = t & 63;
        const int lr = lane & 15, kg = lane >> 4;

        // B fragments: w2f[lr][s*32 + kg*8 .. +8]
        f16x8 bf[4];
        #pragma unroll
        for (int s = 0; s < 4; ++s)
            bf[s] = *(const f16x8*)&w2f[lr][s * 32 + kg * 8];

        // A-gather byte offsets for this lane's k-slices
        int kos[32];
        #pragma unroll
        for (int s = 0; s < 4; ++s)
            #pragma unroll
            for (int j = 0; j < 8; ++j)
                kos[s * 8 + j] = koff[s * 32 + kg * 8 + j];

        const float bias2 = cb2s[lr];
        const char* h1p = (const char*)&h1[0][0][0];
        const int qa = lr & 3;          // pool-window element of this A-row
        const int wa_off = lr >> 2;     // window within tile for A-row

        #pragma unroll 1
        for (int tt = wv_; tt < 43; tt += 4) {
            const int w_A = tt * 4 + wa_off;             // window index 0..171
            const int Y = (w_A * 5042) >> 16;            // w_A / 13 (valid w<176)
            const int X = w_A - Y * 13;
            const int base = (2 * Y + (qa & 1)) * 72 + (2 * X + (qa >> 1)) * 2;
            f32x4 acc = {0.f, 0.f, 0.f, 0.f};
            #pragma unroll
            for (int s = 0; s < 4; ++s) {
                f16x8 af;
                #pragma unroll
                for (int j = 0; j < 8; ++j)
                    af[j] = *(const _Float16*)(h1p + base + kos[s * 8 + j]);
                acc = __builtin_amdgcn_mfma_f32_16x16x32_f16(af, bf[s], acc, 0, 0, 0);
            }
            const int w_C = tt * 4 + kg;
            if (lr < 10 && w_C < 169) {
                const float m = fmaxf(fmaxf(acc[0], acc[1]), fmaxf(acc[2], acc[3]));
                outr[lr * 169 + w_C] = f2h(fmaxf(m + bias2, 0.f));
            }
        }
    }
    if (t < DSD)           outr[1690 + t] = f2h(x[(size_t)b * XW + t]);
    if (t >= DSD && t < 6) outr[1690 + t] = 0;   // zero pad 1693..1695
}

// ---------------------------------------------------------------------------
// Kernel 2: MFMA fp16 GEMM  C[M,N] = [relu](A[M,Kp]f16 @ W[N,Kp]f16^T + bias)
// ---------------------------------------------------------------------------
template <int RELU, int OUTH>
__global__ __launch_bounds__(256) void mfma_fc(
    const short* __restrict__ A,     // [M][Kp] f16
    const short* __restrict__ W,     // [N][Kp] f16
    const float* __restrict__ bias,  // [N]
    void* __restrict__ Cout,         // [M][N] f16 (OUTH) or f32
    int N, int Kp)
{
    __shared__ __align__(16) short As[64][40];
    __shared__ __align__(16) short Ws[64][40];

    const int tid  = threadIdx.x;
    const int m0   = blockIdx.y * 64;
    const int n0   = blockIdx.x * 64;
    const int wv   = tid >> 6, lane = tid & 63;
    const int rm   = (wv >> 1) * 32, rn = (wv & 1) * 32;
    const int lr   = lane & 15, kg = lane >> 4;
    const int sr   = tid >> 2, sc = (tid & 3) * 8;

    f32x4 acc[2][2];
    #pragma unroll
    for (int i = 0; i < 2; ++i)
        #pragma unroll
        for (int j = 0; j < 2; ++j)
            #pragma unroll
            for (int q = 0; q < 4; ++q) acc[i][j][q] = 0.f;

    for (int k0 = 0; k0 < Kp; k0 += 32) {
        *(uint4*)&As[sr][sc] = *(const uint4*)&A[(size_t)(m0 + sr) * Kp + k0 + sc];
        *(uint4*)&Ws[sr][sc] = *(const uint4*)&W[(size_t)(n0 + sr) * Kp + k0 + sc];
        __syncthreads();
        f16x8 aF[2], bF[2];
        #pragma unroll
        for (int mi = 0; mi < 2; ++mi) aF[mi] = *(const f16x8*)&As[rm + mi * 16 + lr][kg * 8];
        #pragma unroll
        for (int nj = 0; nj < 2; ++nj) bF[nj] = *(const f16x8*)&Ws[rn + nj * 16 + lr][kg * 8];
        #pragma unroll
        for (int mi = 0; mi < 2; ++mi)
            #pragma unroll
            for (int nj = 0; nj < 2; ++nj)
                acc[mi][nj] = __builtin_amdgcn_mfma_f32_16x16x32_f16(
                    aF[mi], bF[nj], acc[mi][nj], 0, 0, 0);
        __syncthreads();
    }

    #pragma unroll
    for (int mi = 0; mi < 2; ++mi)
        #pragma unroll
        for (int nj = 0; nj < 2; ++nj) {
            const int col  = n0 + rn + nj * 16 + lr;
            const int rowb = m0 + rm + mi * 16 + kg * 4;
            const float bv = bias[col];
            #pragma unroll
            for (int q = 0; q < 4; ++q) {
                float v = acc[mi][nj][q] + bv;
                if (RELU) v = fmaxf(v, 0.f);
                if (OUTH) ((short*)Cout)[(size_t)(rowb + q) * N + col] = f2h(v);
                else      ((float*)Cout)[(size_t)(rowb + q) * N + col] = v;
            }
        }
}

// ---------------------------------------------------------------------------
// Kernel 3: f32 GEMM for the small tail layers (fc3, fc4)
// ---------------------------------------------------------------------------
template <int RELU>
__global__ __launch_bounds__(256) void gemm_relu(
    const float* __restrict__ A, const float* __restrict__ W,
    const float* __restrict__ bias, float* __restrict__ C,
    int M, int N, int K)
{
    constexpr int BM = 64, BN = 64, BK = 16;
    __shared__ float As[BK][BM + 1];
    __shared__ float Ws[BK][BN + 1];

    const int tid = threadIdx.x;
    const int tx = tid % 16, ty = tid / 16;
    const int m0 = blockIdx.y * BM;
    const int n0 = blockIdx.x * BN;

    float acc[4][4] = {};

    for (int k0 = 0; k0 < K; k0 += BK) {
        for (int i = tid; i < BM * BK; i += 256) {
            const int mm = i / BK, kk = i % BK;
            As[kk][mm] = A[(size_t)(m0 + mm) * K + k0 + kk];
        }
        for (int i = tid; i < BN * BK; i += 256) {
            const int nn = i / BK, kk = i % BK;
            Ws[kk][nn] = W[(size_t)(n0 + nn) * K + k0 + kk];
        }
        __syncthreads();
        #pragma unroll
        for (int kk = 0; kk < BK; ++kk) {
            float a[4], w[4];
            #pragma unroll
            for (int i = 0; i < 4; ++i) a[i] = As[kk][ty * 4 + i];
            #pragma unroll
            for (int j = 0; j < 4; ++j) w[j] = Ws[kk][tx * 4 + j];
            #pragma unroll
            for (int i = 0; i < 4; ++i)
                #pragma unroll
                for (int j = 0; j < 4; ++j)
                    acc[i][j] += a[i] * w[j];
        }
        __syncthreads();
    }

    #pragma unroll
    for (int i = 0; i < 4; ++i) {
        const int m = m0 + ty * 4 + i;
        #pragma unroll
        for (int j = 0; j < 4; ++j) {
            const int n = n0 + tx * 4 + j;
            float v = acc[i][j] + bias[n];
            if (RELU) v = fmaxf(v, 0.f);
            C[(size_t)m * N + n] = v;
        }
    }
}

// ---------------------------------------------------------------------------
// Kernel 4: fc5 + softmax + expert combine -> out[B,3]
// ---------------------------------------------------------------------------
__global__ __launch_bounds__(256) void head_kernel(
    const float* __restrict__ act5, const float* __restrict__ w5,
    const float* __restrict__ b5, const float* __restrict__ Bm,
    const float* __restrict__ Cm, const float* __restrict__ x,
    const float* __restrict__ x_tar, float* __restrict__ out)
{
    __shared__ float sw[16 * 64];
    __shared__ float sb[16];
    __shared__ float sA[16 * 9];
    __shared__ float st[3];
    const int t = threadIdx.x;
    for (int i = t; i < 1024; i += 256) sw[i] = w5[i];
    if (t < 16)  sb[t] = b5[t];
    if (t < 144) sA[t] = Bm[t] + Cm[t];
    if (t < 3)   st[t] = x_tar[t];
    __syncthreads();

    const int b = blockIdx.x * 256 + t;
    float h[64];
    const float* ar = act5 + (size_t)b * 64;
    #pragma unroll
    for (int i = 0; i < 64; ++i) h[i] = ar[i];

    float logit[16];
    float mx = -1e30f;
    #pragma unroll
    for (int n = 0; n < 16; ++n) {
        float s = sb[n];
        const float* wr = sw + n * 64;
        #pragma unroll
        for (int i = 0; i < 64; ++i) s += h[i] * wr[i];
        logit[n] = s;
        mx = fmaxf(mx, s);
    }
    float sum = 0.f;
    #pragma unroll
    for (int n = 0; n < 16; ++n) { logit[n] = __expf(logit[n] - mx); sum += logit[n]; }
    const float inv = 1.f / sum;

    const float d0 = st[0] - x[(size_t)b * XW + 0];
    const float d1 = st[1] - x[(size_t)b * XW + 1];
    const float d2 = st[2] - x[(size_t)b * XW + 2];
    float s0 = 0.f, s1 = 0.f, s2 = 0.f;
    #pragma unroll
    for (int n = 0; n < 16; ++n) {
        const float w = logit[n] * inv;
        const float* An = sA + n * 9;
        s0 += w * (An[0] * d0 + An[1] * d1 + An[2] * d2);
        s1 += w * (An[3] * d0 + An[4] * d1 + An[5] * d2);
        s2 += w * (An[6] * d0 + An[7] * d1 + An[8] * d2);
    }
    out[(size_t)b * 3 + 0] = s0;
    out[(size_t)b * 3 + 1] = s1;
    out[(size_t)b * 3 + 2] = s2;
}

// ---------------------------------------------------------------------------
extern "C" void kernel_launch(void* const* d_in, const int* in_sizes, int n_in,
                              void* d_out, int out_size, void* d_ws, size_t ws_size,
                              hipStream_t stream) {
    const float* x       = (const float*)d_in[0];
    const float* conv1_w = (const float*)d_in[1];
    const float* conv1_b = (const float*)d_in[2];
    const float* conv2_w = (const float*)d_in[3];
    const float* conv2_b = (const float*)d_in[4];
    const float* fc1_w   = (const float*)d_in[5];
    const float* fc1_b   = (const float*)d_in[6];
    const float* fc2_w   = (const float*)d_in[7];
    const float* fc2_b   = (const float*)d_in[8];
    const float* fc3_w   = (const float*)d_in[9];
    const float* fc3_b   = (const float*)d_in[10];
    const float* fc4_w   = (const float*)d_in[11];
    const float* fc4_b   = (const float*)d_in[12];
    const float* fc5_w   = (const float*)d_in[13];
    const float* fc5_b   = (const float*)d_in[14];
    const float* B_mats  = (const float*)d_in[15];
    const float* C_mats  = (const float*)d_in[16];
    const float* x_tar   = (const float*)d_in[17];
    float* out = (float*)d_out;

    char* p = (char*)d_ws;
    short* act1 = (short*)p;  p += (size_t)BSZ * KP1 * 2;   // f16 [8192][1696]
    short* act2 = (short*)p;  p += (size_t)BSZ * 512 * 2;   // f16 [8192][512]
    float* act3 = (float*)p;  p += (size_t)BSZ * 256 * 4;   // f32 [8192][256]
    float* act4 = (float*)p;  p += (size_t)BSZ * 128 * 4;   // f32 [8192][128]
    float* act5 = (float*)p;  p += (size_t)BSZ * 64 * 4;    // f32 [8192][64]
    short* w1h  = (short*)p;  p += (size_t)512 * KP1 * 2;   // f16 [512][1696]
    short* w2h  = (short*)p;  p += (size_t)256 * 512 * 2;   // f16 [256][512]

    cvt_f16_pad<<<1024, 256, 0, stream>>>(fc1_w, w1h, 512, 1693, KP1);
    cvt_f16_pad<<<256,  256, 0, stream>>>(fc2_w, w2h, 256, 512, 512);

    conv_fused<<<BSZ, 256, 0, stream>>>(x, conv1_w, conv1_b, conv2_w, conv2_b, act1);

    mfma_fc<1, 1><<<dim3(512 / 64, BSZ / 64), 256, 0, stream>>>(act1, w1h, fc1_b, act2, 512, KP1);
    mfma_fc<1, 0><<<dim3(256 / 64, BSZ / 64), 256, 0, stream>>>(act2, w2h, fc2_b, act3, 256, 512);

    gemm_relu<1><<<dim3(128 / 64, BSZ / 64), 256, 0, stream>>>(act3, fc3_w, fc3_b, act4, BSZ, 128, 256);
    gemm_relu<1><<<dim3(64 / 64,  BSZ / 64), 256, 0, stream>>>(act4, fc4_w, fc4_b, act5, BSZ, 64, 128);

    head_kernel<<<BSZ / 256, 256, 0, stream>>>(act5, fc5_w, fc5_b, B_mats, C_mats, x, x_tar, out);
}

// Round 7
// 299.560 us; speedup vs baseline: 1.0669x; 1.0669x over previous
//
#include <hip/hip_runtime.h>
#include <hip/hip_bf16.h>
#include <hip/hip_fp16.h>
#include <math.h>

#define XW 4099
#define DSD 3
#define BSZ 8192
#define KP1 1696   // fc1 K padded: 1693 -> 1696 (multiple of 32, 16B-aligned rows)

typedef __attribute__((ext_vector_type(8))) _Float16 f16x8;
typedef __attribute__((ext_vector_type(4))) float    f32x4;

static __device__ __forceinline__ short f2h(float f) {
    union { _Float16 h; short s; } u;
    u.h = (_Float16)f;
    return u.s;
}

// ---------------------------------------------------------------------------
// Kernel 0: f32 -> f16 weight conversion with K-padding.  dst[N][Kp]
// ---------------------------------------------------------------------------
__global__ __launch_bounds__(256) void cvt_f16_pad(
    const float* __restrict__ src, short* __restrict__ dst,
    int N, int K, int Kp)
{
    const int tot = N * Kp;
    for (int i = blockIdx.x * 256 + threadIdx.x; i < tot; i += gridDim.x * 256) {
        const int n = i / Kp, k = i % Kp;
        dst[i] = (k < K) ? f2h(src[(size_t)n * K + k]) : (short)0;
    }
}

// ---------------------------------------------------------------------------
// conv1 channel-group: NC channels' accumulators live (<=32 VGPR) while the
// caller's 8x8 patch (64 VGPR) stays resident. Peak ~106 < 128-reg cap.
// ---------------------------------------------------------------------------
template <int C0, int NC>
__device__ __forceinline__ void conv1_group(
    const f32x4 (&pv)[8][2],
    const float (*cw1t)[8],          // [25][8] transposed weights
    const float* cb1,
    _Float16 (*h1)[32][36],
    int ty, int tx)
{
    float acc[NC][4][4];
    #pragma unroll
    for (int c = 0; c < NC; ++c) {
        const float bias = cb1[C0 + c];
        #pragma unroll
        for (int cy = 0; cy < 4; ++cy)
            #pragma unroll
            for (int cx = 0; cx < 4; ++cx) acc[c][cy][cx] = bias;
    }
    #pragma unroll
    for (int ky = 0; ky < 5; ++ky)
        #pragma unroll
        for (int kx = 0; kx < 5; ++kx) {
            const int kk = ky * 5 + kx;
            float wv[NC];
            if constexpr (NC == 2) {
                const float2 wp = *(const float2*)&cw1t[kk][C0];  // broadcast b64
                wv[0] = wp.x; wv[1] = wp.y;
            } else {
                wv[0] = cw1t[kk][C0];                             // broadcast b32
            }
            #pragma unroll
            for (int cy = 0; cy < 4; ++cy)
                #pragma unroll
                for (int cx = 0; cx < 4; ++cx) {
                    const int px = cx + kx;
                    const float pvv = pv[cy + ky][px >> 2][px & 3];
                    #pragma unroll
                    for (int c = 0; c < NC; ++c)
                        acc[c][cy][cx] += pvv * wv[c];
                }
        }
    #pragma unroll
    for (int c = 0; c < NC; ++c)
        #pragma unroll
        for (int sy = 0; sy < 2; ++sy)
            #pragma unroll
            for (int sx = 0; sx < 2; ++sx) {
                const float m = fmaxf(
                    fmaxf(acc[c][2 * sy][2 * sx],     acc[c][2 * sy][2 * sx + 1]),
                    fmaxf(acc[c][2 * sy + 1][2 * sx], acc[c][2 * sy + 1][2 * sx + 1]));
                h1[C0 + c][2 * ty + sy][2 * tx + sx] = (_Float16)fmaxf(m, 0.f);
            }
}

// ---------------------------------------------------------------------------
// Kernel 1: fused conv. conv1 = f32 VALU, patch loaded ONCE (16 ds_read_b128,
// 64 VGPR resident), channels in groups {0,1}{2,3}{4} so peak pressure fits
// the 4-wave/EU 128-reg budget (waves_per_eu pinned 4,4 -> no spill).
// conv2 = implicit-GEMM on MFMA (validated r5 structure).
// ---------------------------------------------------------------------------
__global__ __attribute__((amdgpu_flat_work_group_size(256, 256), amdgpu_waves_per_eu(4, 4)))
void conv_fused(
    const float* __restrict__ x,
    const float* __restrict__ w1, const float* __restrict__ b1,
    const float* __restrict__ w2, const float* __restrict__ b2,
    short* __restrict__ act1)
{
    __shared__ __align__(16) float     img[64][68];    // 17.4 KB
    __shared__ __align__(16) _Float16  h1[5][32][36];  // 11.5 KB (i-stride 2304 B, row 72 B)
    __shared__ __align__(16) float     cw1t[25][8];    // conv1 w transposed [kpos][ch]
    __shared__ float cb1[5];
    __shared__ __align__(16) _Float16  w2f[16][136];   // conv2 B-matrix [ch][k], padded
    __shared__ float cb2s[16];
    __shared__ unsigned short koff[128];               // k -> byte offset into h1

    const int b = blockIdx.x;
    const int t = threadIdx.x;

    // ---- stage
    const float* xr = x + (size_t)b * XW + DSD;
    #pragma unroll
    for (int i = 0; i < 16; ++i) {
        const int idx = t + 256 * i;
        img[idx >> 6][idx & 63] = xr[idx];
    }
    if (t < 128)
        koff[t] = (t < 125)
            ? (unsigned short)((t / 25) * 2304 + ((t % 25) / 5) * 72 + (t % 5) * 2)
            : (unsigned short)0;
    if (t < 200) {                       // transpose conv1 weights: [kk][c]
        const int kk = t >> 3, c = t & 7;
        cw1t[kk][c] = (c < 5) ? w1[c * 25 + kk] : 0.f;
    }
    if (t >= 208 && t < 213) cb1[t - 208] = b1[t - 208];
    if (t >= 224 && t < 240) cb2s[t - 224] = (t - 224 < 10) ? b2[t - 224] : 0.f;
    for (int i = t; i < 16 * 136; i += 256) {
        const int c = i / 136, k = i % 136;
        _Float16 v = (_Float16)0.f;
        if (c < 10 && k < 125) v = (_Float16)w2[(c * 5 + k / 25) * 25 + (k % 25)];
        w2f[c][k] = v;
    }
    __syncthreads();

    // ---- conv1 + relu + pool (f32 VALU): 15x15 tiles of 2x2 pooled
    if (t < 225) {
        const int ty = t / 15, tx = t % 15;
        const int y0 = 4 * ty, x0 = 4 * tx;
        f32x4 pv[8][2];
        #pragma unroll
        for (int r = 0; r < 8; ++r) {
            pv[r][0] = *(const f32x4*)&img[y0 + r][x0];
            pv[r][1] = *(const f32x4*)&img[y0 + r][x0 + 4];
        }
        conv1_group<0, 2>(pv, cw1t, cb1, h1, ty, tx);
        conv1_group<2, 2>(pv, cw1t, cb1, h1, ty, tx);
        conv1_group<4, 1>(pv, cw1t, cb1, h1, ty, tx);
    }
    __syncthreads();

    // ---- conv2 via MFMA implicit GEMM
    short* outr = act1 + (size_t)b * KP1;
    {
        const int wv_ = t >> 6, lane = t & 63;
        const int lr = lane & 15, kg = lane >> 4;

        // B fragments: w2f[lr][s*32 + kg*8 .. +8]
        f16x8 bf[4];
        #pragma unroll
        for (int s = 0; s < 4; ++s)
            bf[s] = *(const f16x8*)&w2f[lr][s * 32 + kg * 8];

        // A-gather byte offsets for this lane's k-slices
        int kos[32];
        #pragma unroll
        for (int s = 0; s < 4; ++s)
            #pragma unroll
            for (int j = 0; j < 8; ++j)
                kos[s * 8 + j] = koff[s * 32 + kg * 8 + j];

        const float bias2 = cb2s[lr];
        const char* h1p = (const char*)&h1[0][0][0];
        const int qa = lr & 3;          // pool-window element of this A-row
        const int wa_off = lr >> 2;     // window within tile for A-row

        #pragma unroll 1
        for (int tt = wv_; tt < 43; tt += 4) {
            const int w_A = tt * 4 + wa_off;             // window index 0..171
            const int Y = (w_A * 5042) >> 16;            // w_A / 13 (valid w<176)
            const int X = w_A - Y * 13;
            const int base = (2 * Y + (qa & 1)) * 72 + (2 * X + (qa >> 1)) * 2;
            f32x4 acc = {0.f, 0.f, 0.f, 0.f};
            #pragma unroll
            for (int s = 0; s < 4; ++s) {
                f16x8 af;
                #pragma unroll
                for (int j = 0; j < 8; ++j)
                    af[j] = *(const _Float16*)(h1p + base + kos[s * 8 + j]);
                acc = __builtin_amdgcn_mfma_f32_16x16x32_f16(af, bf[s], acc, 0, 0, 0);
            }
            const int w_C = tt * 4 + kg;
            if (lr < 10 && w_C < 169) {
                const float m = fmaxf(fmaxf(acc[0], acc[1]), fmaxf(acc[2], acc[3]));
                outr[lr * 169 + w_C] = f2h(fmaxf(m + bias2, 0.f));
            }
        }
    }
    if (t < DSD)           outr[1690 + t] = f2h(x[(size_t)b * XW + t]);
    if (t >= DSD && t < 6) outr[1690 + t] = 0;   // zero pad 1693..1695
}

// ---------------------------------------------------------------------------
// Kernel 2: MFMA fp16 GEMM  C[M,N] = [relu](A[M,Kp]f16 @ W[N,Kp]f16^T + bias)
// ---------------------------------------------------------------------------
template <int RELU, int OUTH>
__global__ __launch_bounds__(256) void mfma_fc(
    const short* __restrict__ A,     // [M][Kp] f16
    const short* __restrict__ W,     // [N][Kp] f16
    const float* __restrict__ bias,  // [N]
    void* __restrict__ Cout,         // [M][N] f16 (OUTH) or f32
    int N, int Kp)
{
    __shared__ __align__(16) short As[64][40];
    __shared__ __align__(16) short Ws[64][40];

    const int tid  = threadIdx.x;
    const int m0   = blockIdx.y * 64;
    const int n0   = blockIdx.x * 64;
    const int wv   = tid >> 6, lane = tid & 63;
    const int rm   = (wv >> 1) * 32, rn = (wv & 1) * 32;
    const int lr   = lane & 15, kg = lane >> 4;
    const int sr   = tid >> 2, sc = (tid & 3) * 8;

    f32x4 acc[2][2];
    #pragma unroll
    for (int i = 0; i < 2; ++i)
        #pragma unroll
        for (int j = 0; j < 2; ++j)
            #pragma unroll
            for (int q = 0; q < 4; ++q) acc[i][j][q] = 0.f;

    for (int k0 = 0; k0 < Kp; k0 += 32) {
        *(uint4*)&As[sr][sc] = *(const uint4*)&A[(size_t)(m0 + sr) * Kp + k0 + sc];
        *(uint4*)&Ws[sr][sc] = *(const uint4*)&W[(size_t)(n0 + sr) * Kp + k0 + sc];
        __syncthreads();
        f16x8 aF[2], bF[2];
        #pragma unroll
        for (int mi = 0; mi < 2; ++mi) aF[mi] = *(const f16x8*)&As[rm + mi * 16 + lr][kg * 8];
        #pragma unroll
        for (int nj = 0; nj < 2; ++nj) bF[nj] = *(const f16x8*)&Ws[rn + nj * 16 + lr][kg * 8];
        #pragma unroll
        for (int mi = 0; mi < 2; ++mi)
            #pragma unroll
            for (int nj = 0; nj < 2; ++nj)
                acc[mi][nj] = __builtin_amdgcn_mfma_f32_16x16x32_f16(
                    aF[mi], bF[nj], acc[mi][nj], 0, 0, 0);
        __syncthreads();
    }

    #pragma unroll
    for (int mi = 0; mi < 2; ++mi)
        #pragma unroll
        for (int nj = 0; nj < 2; ++nj) {
            const int col  = n0 + rn + nj * 16 + lr;
            const int rowb = m0 + rm + mi * 16 + kg * 4;
            const float bv = bias[col];
            #pragma unroll
            for (int q = 0; q < 4; ++q) {
                float v = acc[mi][nj][q] + bv;
                if (RELU) v = fmaxf(v, 0.f);
                if (OUTH) ((short*)Cout)[(size_t)(rowb + q) * N + col] = f2h(v);
                else      ((float*)Cout)[(size_t)(rowb + q) * N + col] = v;
            }
        }
}

// ---------------------------------------------------------------------------
// Kernel 3: f32 GEMM for the small tail layers (fc3, fc4)
// ---------------------------------------------------------------------------
template <int RELU>
__global__ __launch_bounds__(256) void gemm_relu(
    const float* __restrict__ A, const float* __restrict__ W,
    const float* __restrict__ bias, float* __restrict__ C,
    int M, int N, int K)
{
    constexpr int BM = 64, BN = 64, BK = 16;
    __shared__ float As[BK][BM + 1];
    __shared__ float Ws[BK][BN + 1];

    const int tid = threadIdx.x;
    const int tx = tid % 16, ty = tid / 16;
    const int m0 = blockIdx.y * BM;
    const int n0 = blockIdx.x * BN;

    float acc[4][4] = {};

    for (int k0 = 0; k0 < K; k0 += BK) {
        for (int i = tid; i < BM * BK; i += 256) {
            const int mm = i / BK, kk = i % BK;
            As[kk][mm] = A[(size_t)(m0 + mm) * K + k0 + kk];
        }
        for (int i = tid; i < BN * BK; i += 256) {
            const int nn = i / BK, kk = i % BK;
            Ws[kk][nn] = W[(size_t)(n0 + nn) * K + k0 + kk];
        }
        __syncthreads();
        #pragma unroll
        for (int kk = 0; kk < BK; ++kk) {
            float a[4], w[4];
            #pragma unroll
            for (int i = 0; i < 4; ++i) a[i] = As[kk][ty * 4 + i];
            #pragma unroll
            for (int j = 0; j < 4; ++j) w[j] = Ws[kk][tx * 4 + j];
            #pragma unroll
            for (int i = 0; i < 4; ++i)
                #pragma unroll
                for (int j = 0; j < 4; ++j)
                    acc[i][j] += a[i] * w[j];
        }
        __syncthreads();
    }

    #pragma unroll
    for (int i = 0; i < 4; ++i) {
        const int m = m0 + ty * 4 + i;
        #pragma unroll
        for (int j = 0; j < 4; ++j) {
            const int n = n0 + tx * 4 + j;
            float v = acc[i][j] + bias[n];
            if (RELU) v = fmaxf(v, 0.f);
            C[(size_t)m * N + n] = v;
        }
    }
}

// ---------------------------------------------------------------------------
// Kernel 4: fc5 + softmax + expert combine -> out[B,3]
// ---------------------------------------------------------------------------
__global__ __launch_bounds__(256) void head_kernel(
    const float* __restrict__ act5, const float* __restrict__ w5,
    const float* __restrict__ b5, const float* __restrict__ Bm,
    const float* __restrict__ Cm, const float* __restrict__ x,
    const float* __restrict__ x_tar, float* __restrict__ out)
{
    __shared__ float sw[16 * 64];
    __shared__ float sb[16];
    __shared__ float sA[16 * 9];
    __shared__ float st[3];
    const int t = threadIdx.x;
    for (int i = t; i < 1024; i += 256) sw[i] = w5[i];
    if (t < 16)  sb[t] = b5[t];
    if (t < 144) sA[t] = Bm[t] + Cm[t];
    if (t < 3)   st[t] = x_tar[t];
    __syncthreads();

    const int b = blockIdx.x * 256 + t;
    float h[64];
    const float* ar = act5 + (size_t)b * 64;
    #pragma unroll
    for (int i = 0; i < 64; ++i) h[i] = ar[i];

    float logit[16];
    float mx = -1e30f;
    #pragma unroll
    for (int n = 0; n < 16; ++n) {
        float s = sb[n];
        const float* wr = sw + n * 64;
        #pragma unroll
        for (int i = 0; i < 64; ++i) s += h[i] * wr[i];
        logit[n] = s;
        mx = fmaxf(mx, s);
    }
    float sum = 0.f;
    #pragma unroll
    for (int n = 0; n < 16; ++n) { logit[n] = __expf(logit[n] - mx); sum += logit[n]; }
    const float inv = 1.f / sum;

    const float d0 = st[0] - x[(size_t)b * XW + 0];
    const float d1 = st[1] - x[(size_t)b * XW + 1];
    const float d2 = st[2] - x[(size_t)b * XW + 2];
    float s0 = 0.f, s1 = 0.f, s2 = 0.f;
    #pragma unroll
    for (int n = 0; n < 16; ++n) {
        const float w = logit[n] * inv;
        const float* An = sA + n * 9;
        s0 += w * (An[0] * d0 + An[1] * d1 + An[2] * d2);
        s1 += w * (An[3] * d0 + An[4] * d1 + An[5] * d2);
        s2 += w * (An[6] * d0 + An[7] * d1 + An[8] * d2);
    }
    out[(size_t)b * 3 + 0] = s0;
    out[(size_t)b * 3 + 1] = s1;
    out[(size_t)b * 3 + 2] = s2;
}

// ---------------------------------------------------------------------------
extern "C" void kernel_launch(void* const* d_in, const int* in_sizes, int n_in,
                              void* d_out, int out_size, void* d_ws, size_t ws_size,
                              hipStream_t stream) {
    const float* x       = (const float*)d_in[0];
    const float* conv1_w = (const float*)d_in[1];
    const float* conv1_b = (const float*)d_in[2];
    const float* conv2_w = (const float*)d_in[3];
    const float* conv2_b = (const float*)d_in[4];
    const float* fc1_w   = (const float*)d_in[5];
    const float* fc1_b   = (const float*)d_in[6];
    const float* fc2_w   = (const float*)d_in[7];
    const float* fc2_b   = (const float*)d_in[8];
    const float* fc3_w   = (const float*)d_in[9];
    const float* fc3_b   = (const float*)d_in[10];
    const float* fc4_w   = (const float*)d_in[11];
    const float* fc4_b   = (const float*)d_in[12];
    const float* fc5_w   = (const float*)d_in[13];
    const float* fc5_b   = (const float*)d_in[14];
    const float* B_mats  = (const float*)d_in[15];
    const float* C_mats  = (const float*)d_in[16];
    const float* x_tar   = (const float*)d_in[17];
    float* out = (float*)d_out;

    char* p = (char*)d_ws;
    short* act1 = (short*)p;  p += (size_t)BSZ * KP1 * 2;   // f16 [8192][1696]
    short* act2 = (short*)p;  p += (size_t)BSZ * 512 * 2;   // f16 [8192][512]
    float* act3 = (float*)p;  p += (size_t)BSZ * 256 * 4;   // f32 [8192][256]
    float* act4 = (float*)p;  p += (size_t)BSZ * 128 * 4;   // f32 [8192][128]
    float* act5 = (float*)p;  p += (size_t)BSZ * 64 * 4;    // f32 [8192][64]
    short* w1h  = (short*)p;  p += (size_t)512 * KP1 * 2;   // f16 [512][1696]
    short* w2h  = (short*)p;  p += (size_t)256 * 512 * 2;   // f16 [256][512]

    cvt_f16_pad<<<1024, 256, 0, stream>>>(fc1_w, w1h, 512, 1693, KP1);
    cvt_f16_pad<<<256,  256, 0, stream>>>(fc2_w, w2h, 256, 512, 512);

    conv_fused<<<BSZ, 256, 0, stream>>>(x, conv1_w, conv1_b, conv2_w, conv2_b, act1);

    mfma_fc<1, 1><<<dim3(512 / 64, BSZ / 64), 256, 0, stream>>>(act1, w1h, fc1_b, act2, 512, KP1);
    mfma_fc<1, 0><<<dim3(256 / 64, BSZ / 64), 256, 0, stream>>>(act2, w2h, fc2_b, act3, 256, 512);

    gemm_relu<1><<<dim3(128 / 64, BSZ / 64), 256, 0, stream>>>(act3, fc3_w, fc3_b, act4, BSZ, 128, 256);
    gemm_relu<1><<<dim3(64 / 64,  BSZ / 64), 256, 0, stream>>>(act4, fc4_w, fc4_b, act5, BSZ, 64, 128);

    head_kernel<<<BSZ / 256, 256, 0, stream>>>(act5, fc5_w, fc5_b, B_mats, C_mats, x, x_tar, out);
}